// Round 1
// baseline (114.588 us; speedup 1.0000x reference)
//
#include <hip/hip_runtime.h>
#include <hip/hip_bf16.h>

#define N_VOX 100000
#define C_IN  32
#define C_OUT 64
#define KOFF  27
// waves of 64 voxels: ceil(100000/64)=1563 waves; 4 waves/block -> 391 blocks
#define NB_CONV 391

typedef __attribute__((ext_vector_type(8))) short bf16x8_t;
typedef __attribute__((ext_vector_type(4))) float f32x4_t;

__device__ __forceinline__ short f2bf(float f) {
    __hip_bfloat16 h = __float2bfloat16(f);
    return __builtin_bit_cast(short, h);
}

// Wt[k][d][c] = bf16(W[k][c][d])  -- so B-fragments are contiguous 16B per lane
__global__ void prep_w_kernel(const float* __restrict__ W,
                              unsigned short* __restrict__ Wt) {
    int i = blockIdx.x * 256 + threadIdx.x;
    if (i >= KOFF * C_OUT * C_IN) return;
    int c = i & 31;
    int d = (i >> 5) & 63;
    int k = i >> 11;
    float v = W[k * (C_IN * C_OUT) + c * C_OUT + d];
    Wt[i] = (unsigned short)f2bf(v);
}

__global__ __launch_bounds__(256) void conv_kernel(
    const float* __restrict__ feat, const int* __restrict__ nidx,
    const unsigned short* __restrict__ Wt, float* __restrict__ out,
    float* __restrict__ partials)
{
    __shared__ float lsum[4][C_OUT];
    __shared__ float lsq[4][C_OUT];

    const int wid  = threadIdx.x >> 6;
    const int lane = threadIdx.x & 63;
    const int colr = lane & 15;   // A: voxel row within tile; B/C: channel col
    const int kch  = lane >> 4;   // k-chunk 0..3
    const int c0   = kch * 8;     // input-channel start for A/B fragment
    const int wave = blockIdx.x * 4 + wid;
    const int base = wave * 64;

    f32x4_t acc[4][4];
    #pragma unroll
    for (int m = 0; m < 4; ++m)
        #pragma unroll
        for (int t = 0; t < 4; ++t) acc[m][t] = (f32x4_t)0.0f;

    for (int k = 0; k < KOFF; ++k) {
        bf16x8_t a[4];
        bool anyv[4];
        #pragma unroll
        for (int m = 0; m < 4; ++m) {
            int vox = base + m * 16 + colr;
            int idx = -1;
            if (vox < N_VOX) idx = nidx[vox * KOFF + k];
            anyv[m] = __any(idx >= 0);
            bf16x8_t av = (bf16x8_t)(short)0;
            if (idx >= 0) {
                const f32x4_t* fp = (const f32x4_t*)(feat + (idx << 5) + c0);
                f32x4_t f0 = fp[0];
                f32x4_t f1 = fp[1];
                av[0] = f2bf(f0[0]); av[1] = f2bf(f0[1]);
                av[2] = f2bf(f0[2]); av[3] = f2bf(f0[3]);
                av[4] = f2bf(f1[0]); av[5] = f2bf(f1[1]);
                av[6] = f2bf(f1[2]); av[7] = f2bf(f1[3]);
            }
            a[m] = av;
        }
        const unsigned short* wk = Wt + k * (C_OUT * C_IN);
        #pragma unroll
        for (int t = 0; t < 4; ++t) {
            bf16x8_t b = *(const bf16x8_t*)(wk + (t * 16 + colr) * C_IN + c0);
            #pragma unroll
            for (int m = 0; m < 4; ++m) {
                if (anyv[m])
                    acc[m][t] = __builtin_amdgcn_mfma_f32_16x16x32_bf16(
                        a[m], b, acc[m][t], 0, 0, 0);
            }
        }
    }

    // epilogue: store pre-BN conv output + per-channel partial sums
    // C/D layout: col = lane&15, row = (lane>>4)*4 + i   [verified mapping]
    float psum[4], psq[4];
    #pragma unroll
    for (int t = 0; t < 4; ++t) { psum[t] = 0.f; psq[t] = 0.f; }

    #pragma unroll
    for (int m = 0; m < 4; ++m) {
        #pragma unroll
        for (int t = 0; t < 4; ++t) {
            #pragma unroll
            for (int i = 0; i < 4; ++i) {
                int vox = base + m * 16 + kch * 4 + i;
                float v = acc[m][t][i];
                if (vox < N_VOX) out[vox * C_OUT + t * 16 + colr] = v;
                psum[t] += v;       // rows >= N_VOX are exactly 0 -> harmless
                psq[t]  += v * v;
            }
        }
    }

    #pragma unroll
    for (int t = 0; t < 4; ++t) {
        psum[t] += __shfl_xor(psum[t], 16);
        psum[t] += __shfl_xor(psum[t], 32);
        psq[t]  += __shfl_xor(psq[t], 16);
        psq[t]  += __shfl_xor(psq[t], 32);
    }
    if (lane < 16) {
        #pragma unroll
        for (int t = 0; t < 4; ++t) {
            lsum[wid][t * 16 + lane] = psum[t];
            lsq[wid][t * 16 + lane]  = psq[t];
        }
    }
    __syncthreads();
    if (threadIdx.x < C_OUT) {
        int c = threadIdx.x;
        float s = lsum[0][c] + lsum[1][c] + lsum[2][c] + lsum[3][c];
        float q = lsq[0][c] + lsq[1][c] + lsq[2][c] + lsq[3][c];
        partials[blockIdx.x * 128 + c]      = s;
        partials[blockIdx.x * 128 + 64 + c] = q;
    }
}

__global__ void stats_kernel(const float* __restrict__ partials,
                             const float* __restrict__ gamma,
                             const float* __restrict__ beta,
                             float* __restrict__ ss)
{
    __shared__ float ls[4][C_OUT];
    __shared__ float lq[4][C_OUT];
    int c = threadIdx.x & 63;
    int p = threadIdx.x >> 6;
    float s = 0.f, q = 0.f;
    #pragma unroll 4
    for (int b = p; b < NB_CONV; b += 4) {
        s += partials[b * 128 + c];
        q += partials[b * 128 + 64 + c];
    }
    ls[p][c] = s; lq[p][c] = q;
    __syncthreads();
    if (threadIdx.x < C_OUT) {
        float S = ls[0][c] + ls[1][c] + ls[2][c] + ls[3][c];
        float Q = lq[0][c] + lq[1][c] + lq[2][c] + lq[3][c];
        float mean = S * (1.0f / N_VOX);
        float var  = Q * (1.0f / N_VOX) - mean * mean;
        float inv  = rsqrtf(var + 1e-5f);
        float sc   = gamma[c] * inv;
        ss[c]      = sc;
        ss[64 + c] = beta[c] - mean * sc;
    }
}

__global__ void bn_relu_kernel(float* __restrict__ out,
                               const float* __restrict__ ss) {
    int i = blockIdx.x * 256 + threadIdx.x;  // exactly N*64/4 threads
    f32x4_t v = ((f32x4_t*)out)[i];
    int d0 = (i * 4) & 63;
    f32x4_t sc = *(const f32x4_t*)(ss + d0);
    f32x4_t sh = *(const f32x4_t*)(ss + 64 + d0);
    #pragma unroll
    for (int j = 0; j < 4; ++j) v[j] = fmaxf(v[j] * sc[j] + sh[j], 0.f);
    ((f32x4_t*)out)[i] = v;
}

extern "C" void kernel_launch(void* const* d_in, const int* in_sizes, int n_in,
                              void* d_out, int out_size, void* d_ws, size_t ws_size,
                              hipStream_t stream) {
    const float* feat  = (const float*)d_in[0];
    const int*   nidx  = (const int*)d_in[1];
    const float* W     = (const float*)d_in[2];
    const float* gamma = (const float*)d_in[3];
    const float* beta  = (const float*)d_in[4];
    float* out = (float*)d_out;

    char* ws = (char*)d_ws;
    unsigned short* Wt = (unsigned short*)ws;                  // 110592 B
    float* partials = (float*)(ws + 110592);                   // 391*128*4 B
    float* ss       = (float*)(ws + 110592 + NB_CONV * 512);   // 128 f32

    int wt_elems = KOFF * C_OUT * C_IN;
    prep_w_kernel<<<(wt_elems + 255) / 256, 256, 0, stream>>>(W, Wt);
    conv_kernel<<<NB_CONV, 256, 0, stream>>>(feat, nidx, Wt, out, partials);
    stats_kernel<<<1, 256, 0, stream>>>(partials, gamma, beta, ss);
    bn_relu_kernel<<<(N_VOX * C_OUT / 4 + 255) / 256, 256, 0, stream>>>(out, ss);
}

// Round 2
// 83.832 us; speedup vs baseline: 1.3669x; 1.3669x over previous
//
#include <hip/hip_runtime.h>
#include <hip/hip_bf16.h>

#define N_VOX 100000
#define C_IN  32
#define C_OUT 64
#define KOFF  27
// 16 voxels per wave, 4 waves (64 voxels) per block
#define NB_CONV 1563   // ceil(100000/64)

typedef __attribute__((ext_vector_type(8))) short bf16x8_t;
typedef __attribute__((ext_vector_type(4))) float f32x4_t;

__device__ __forceinline__ short f2bf(float f) {
    __hip_bfloat16 h = __float2bfloat16(f);
    return __builtin_bit_cast(short, h);
}

// Wt[k][d][c] = bf16(W[k][c][d])  -- B-fragments contiguous 16B per lane
__global__ void prep_w_kernel(const float* __restrict__ W,
                              unsigned short* __restrict__ Wt) {
    int i = blockIdx.x * 256 + threadIdx.x;
    if (i >= KOFF * C_OUT * C_IN) return;
    int c = i & 31;
    int d = (i >> 5) & 63;
    int k = i >> 11;
    Wt[i] = (unsigned short)f2bf(W[k * (C_IN * C_OUT) + c * C_OUT + d]);
}

__global__ __launch_bounds__(256) void conv_kernel(
    const float* __restrict__ feat, const int* __restrict__ nidx,
    const unsigned short* __restrict__ Wt, float* __restrict__ out,
    float* __restrict__ partials)
{
    __shared__ float lsum[4][C_OUT];
    __shared__ float lsq[4][C_OUT];

    const int wid  = threadIdx.x >> 6;
    const int lane = threadIdx.x & 63;
    const int colr = lane & 15;   // A row (voxel within tile) / C col (channel)
    const int kch  = lane >> 4;   // k-chunk 0..3
    const int c0   = kch * 8;     // input-channel start for A/B fragment
    const int base = blockIdx.x * 64 + wid * 16;
    const int vox  = base + colr; // voxel whose neighbors this lane gathers

    f32x4_t acc[4];
    #pragma unroll
    for (int t = 0; t < 4; ++t) acc[t] = (f32x4_t)0.0f;

    const int* nrow = nidx + vox * KOFF;
    const bool valid = (vox < N_VOX);
    int idx = valid ? nrow[0] : -1;

    for (int k = 0; k < KOFF; ++k) {
        int idx_next = (k < KOFF - 1 && valid) ? nrow[k + 1] : -1;
        if (__any(idx >= 0)) {
            bf16x8_t a = (bf16x8_t)(short)0;
            if (idx >= 0) {
                const f32x4_t* fp = (const f32x4_t*)(feat + (idx << 5) + c0);
                f32x4_t f0 = fp[0];
                f32x4_t f1 = fp[1];
                a[0] = f2bf(f0[0]); a[1] = f2bf(f0[1]);
                a[2] = f2bf(f0[2]); a[3] = f2bf(f0[3]);
                a[4] = f2bf(f1[0]); a[5] = f2bf(f1[1]);
                a[6] = f2bf(f1[2]); a[7] = f2bf(f1[3]);
            }
            const unsigned short* wk = Wt + k * (C_OUT * C_IN);
            #pragma unroll
            for (int t = 0; t < 4; ++t) {
                bf16x8_t b = *(const bf16x8_t*)(wk + (t * 16 + colr) * C_IN + c0);
                acc[t] = __builtin_amdgcn_mfma_f32_16x16x32_bf16(a, b, acc[t], 0, 0, 0);
            }
        }
        idx = idx_next;
    }

    // epilogue: C/D layout col = lane&15, row = (lane>>4)*4 + i
    float psum[4], psq[4];
    #pragma unroll
    for (int t = 0; t < 4; ++t) { psum[t] = 0.f; psq[t] = 0.f; }

    #pragma unroll
    for (int t = 0; t < 4; ++t) {
        #pragma unroll
        for (int i = 0; i < 4; ++i) {
            int v = base + kch * 4 + i;
            float x = acc[t][i];
            if (v < N_VOX) out[v * C_OUT + t * 16 + colr] = x;
            psum[t] += x;           // rows >= N_VOX are exactly 0
            psq[t]  += x * x;
        }
    }

    #pragma unroll
    for (int t = 0; t < 4; ++t) {
        psum[t] += __shfl_xor(psum[t], 16);
        psum[t] += __shfl_xor(psum[t], 32);
        psq[t]  += __shfl_xor(psq[t], 16);
        psq[t]  += __shfl_xor(psq[t], 32);
    }
    if (lane < 16) {
        #pragma unroll
        for (int t = 0; t < 4; ++t) {
            lsum[wid][t * 16 + lane] = psum[t];
            lsq[wid][t * 16 + lane]  = psq[t];
        }
    }
    __syncthreads();
    // channel-major partials: rows 0..63 = sum[c], rows 64..127 = sumsq[c]
    if (threadIdx.x < 128) {
        int c = threadIdx.x & 63;
        float s;
        if (threadIdx.x < 64)
            s = lsum[0][c] + lsum[1][c] + lsum[2][c] + lsum[3][c];
        else
            s = lsq[0][c] + lsq[1][c] + lsq[2][c] + lsq[3][c];
        partials[threadIdx.x * NB_CONV + blockIdx.x] = s;
    }
}

// one block per output channel: coalesced reduction over NB_CONV partials
__global__ __launch_bounds__(256) void stats_kernel(
    const float* __restrict__ partials,
    const float* __restrict__ gamma, const float* __restrict__ beta,
    float* __restrict__ ss)
{
    __shared__ float bs[4], bq[4];
    const int c = blockIdx.x;
    const float* ps = partials + c * NB_CONV;
    const float* pq = partials + (64 + c) * NB_CONV;
    float s = 0.f, q = 0.f;
    for (int i = threadIdx.x; i < NB_CONV; i += 256) {
        s += ps[i];
        q += pq[i];
    }
    #pragma unroll
    for (int o = 1; o < 64; o <<= 1) {
        s += __shfl_xor(s, o);
        q += __shfl_xor(q, o);
    }
    int wid = threadIdx.x >> 6, lane = threadIdx.x & 63;
    if (lane == 0) { bs[wid] = s; bq[wid] = q; }
    __syncthreads();
    if (threadIdx.x == 0) {
        float S = bs[0] + bs[1] + bs[2] + bs[3];
        float Q = bq[0] + bq[1] + bq[2] + bq[3];
        float mean = S * (1.0f / N_VOX);
        float var  = Q * (1.0f / N_VOX) - mean * mean;
        float inv  = rsqrtf(var + 1e-5f);
        float sc   = gamma[c] * inv;
        ss[c]      = sc;
        ss[64 + c] = beta[c] - mean * sc;
    }
}

__global__ void bn_relu_kernel(float* __restrict__ out,
                               const float* __restrict__ ss) {
    int i = blockIdx.x * 256 + threadIdx.x;  // exactly N*64/4 threads
    f32x4_t v = ((f32x4_t*)out)[i];
    int d0 = (i * 4) & 63;
    f32x4_t sc = *(const f32x4_t*)(ss + d0);
    f32x4_t sh = *(const f32x4_t*)(ss + 64 + d0);
    #pragma unroll
    for (int j = 0; j < 4; ++j) v[j] = fmaxf(v[j] * sc[j] + sh[j], 0.f);
    ((f32x4_t*)out)[i] = v;
}

extern "C" void kernel_launch(void* const* d_in, const int* in_sizes, int n_in,
                              void* d_out, int out_size, void* d_ws, size_t ws_size,
                              hipStream_t stream) {
    const float* feat  = (const float*)d_in[0];
    const int*   nidx  = (const int*)d_in[1];
    const float* W     = (const float*)d_in[2];
    const float* gamma = (const float*)d_in[3];
    const float* beta  = (const float*)d_in[4];
    float* out = (float*)d_out;

    char* ws = (char*)d_ws;
    unsigned short* Wt = (unsigned short*)ws;                     // 110592 B
    float* partials = (float*)(ws + 110592);                      // 128*1563*4 B
    float* ss       = (float*)(ws + 110592 + 128 * NB_CONV * 4);  // 128 f32

    int wt_elems = KOFF * C_OUT * C_IN;
    prep_w_kernel<<<(wt_elems + 255) / 256, 256, 0, stream>>>(W, Wt);
    conv_kernel<<<NB_CONV, 256, 0, stream>>>(feat, nidx, Wt, out, partials);
    stats_kernel<<<C_OUT, 256, 0, stream>>>(partials, gamma, beta, ss);
    bn_relu_kernel<<<(N_VOX * C_OUT / 4 + 255) / 256, 256, 0, stream>>>(out, ss);
}